// Round 5
// baseline (164.099 us; speedup 1.0000x reference)
//
#include <hip/hip_runtime.h>

#define TPB 256
#define NW (TPB / 64)
#define NCOLS 16384
#define F4PT (NCOLS / 4 / TPB)    // 16 float4 loads per thread
#define BINS1 4096
#define SH1 19                    // key >> 19 -> 12-bit bin
#define CAP1 512                  // candidate capacity (expected E1 ~ 290)

typedef float f32x4 __attribute__((ext_vector_type(4)));

__device__ __forceinline__ unsigned keyOf(float f) {
    return __float_as_uint(f) & 0x7fffffffu;
}

// Block-wide descending (suffix) select over hist[NBINS]: finds bin b s.t.
// sum(hist[b..NBINS-1]) first reaches >= Krem scanning from the top.
// bc[0]=cut bin, bc[1]=quota within bin, bc[2]=bin population.
// Caller synced hist; ends with __syncthreads().
template <int NBINS>
__device__ void suffix_select(const unsigned* hist, unsigned Krem,
                              unsigned* wsums, unsigned* bc) {
    const int t = threadIdx.x;
    const int lane = t & 63;
    const int wave = t >> 6;
    constexpr int CH = (NBINS + TPB - 1) / TPB;
    const int base = t * CH;
    unsigned c = 0;
#pragma unroll
    for (int i = 0; i < CH; ++i)
        if (base + i < NBINS) c += hist[base + i];
    unsigned s = c;   // in-wave inclusive suffix scan
#pragma unroll
    for (int off = 1; off < 64; off <<= 1) {
        unsigned o = __shfl_down(s, off);
        if (lane + off < 64) s += o;
    }
    if (lane == 0) wsums[wave] = s;
    __syncthreads();
    if (wave == 0) {
        unsigned ws = (lane < NW) ? wsums[lane] : 0u;
        unsigned ss = ws;
#pragma unroll
        for (int off = 1; off < NW; off <<= 1) {
            unsigned o = __shfl_down(ss, off);
            if (lane + off < NW) ss += o;
        }
        if (lane < NW) wsums[lane] = ss;
    }
    __syncthreads();
    unsigned gts = ((wave + 1 < NW) ? wsums[wave + 1] : 0u) + (s - c);
    if (gts < Krem && gts + c >= Krem) {  // exactly one thread brackets the cut
        unsigned cum = gts;
        for (int i = CH - 1; i >= 0; --i) {
            if (base + i >= NBINS) continue;
            unsigned h = hist[base + i];
            cum += h;
            if (cum >= Krem) {
                bc[0] = (unsigned)(base + i);
                bc[1] = Krem - (cum - h);
                bc[2] = h;
                break;
            }
        }
    }
    __syncthreads();
}

__global__ __launch_bounds__(TPB, 8) void topk_mask_kernel(
        const float* __restrict__ x, const int* __restrict__ kp,
        float* __restrict__ out) {
    __shared__ unsigned hist[BINS1];          // 16 KB; overlaid below after use
    __shared__ unsigned bitmap[NCOLS / 32];   // 2 KB keep-bits for tie class
    __shared__ unsigned wsums[NW];
    __shared__ unsigned bc[3];
    __shared__ unsigned cnt;

    // hist is dead after suffix_select<BINS1>; reuse its space.
    unsigned* candKey = hist;                 // [0 .. CAP1)
    unsigned* candIdx = hist + CAP1;          // [CAP1 .. 2*CAP1)
    unsigned* hist2   = hist + 2 * CAP1;      // 256 bins (rare refine path)

    const int t = threadIdx.x;
    const unsigned K = (unsigned)(*kp);
    const float4* xr =
        reinterpret_cast<const float4*>(x) + (size_t)blockIdx.x * (NCOLS / 4);
    f32x4* orow =
        reinterpret_cast<f32x4*>(out) + (size_t)blockIdx.x * (NCOLS / 4);

    // zero hist + bitmap + cnt (contiguous per thread -> b128 stores)
    {
        constexpr int ZH = BINS1 / TPB;        // 16
#pragma unroll
        for (int i = 0; i < ZH; ++i) hist[t * ZH + i] = 0u;
        constexpr int ZB = (NCOLS / 32) / TPB; // 2
#pragma unroll
        for (int i = 0; i < ZB; ++i) bitmap[t * ZB + i] = 0u;
        if (t == 0) cnt = 0u;
    }
    __syncthreads();

    // ---------- pass 1: stream row from HBM, 12-bit histogram ----------
#pragma unroll 4
    for (int i = 0; i < F4PT; ++i) {
        float4 v = xr[t + i * TPB];
        atomicAdd(&hist[keyOf(v.x) >> SH1], 1u);
        atomicAdd(&hist[keyOf(v.y) >> SH1], 1u);
        atomicAdd(&hist[keyOf(v.z) >> SH1], 1u);
        atomicAdd(&hist[keyOf(v.w) >> SH1], 1u);
    }
    __syncthreads();
    suffix_select<BINS1>(hist, K, wsums, bc);
    unsigned p = bc[0];   // prefix value at shift s
    unsigned r = bc[1];   // quota among elements with (key>>s)==p
    unsigned E = bc[2];   // population of that class
    unsigned s = SH1;

    // ---------- rare: refine prefix by 8 bits until class fits CAP1 ----------
    while (E > CAP1 && s > 0) {
        unsigned sh2 = (s >= 8) ? (s - 8) : 0u;
        unsigned width = s - sh2;
        unsigned mask = (1u << width) - 1u;
        if (t < 256) hist2[t] = 0u;
        __syncthreads();
#pragma unroll 2
        for (int i = 0; i < F4PT; ++i) {
            float4 v = xr[t + i * TPB];
#pragma unroll
            for (int j = 0; j < 4; ++j) {
                unsigned key = keyOf((&v.x)[j]);
                if ((key >> s) == p) atomicAdd(&hist2[(key >> sh2) & mask], 1u);
            }
        }
        __syncthreads();
        suffix_select<256>(hist2, r, wsums, bc);
        p = (p << width) | bc[0];
        r = bc[1];
        E = bc[2];
        s = sh2;
    }

    const bool keepAll = (r == E);   // whole class kept -> no ranking needed
    if (!keepAll) {
        // compact the candidate class to LDS (L2-hot re-read)
#pragma unroll 2
        for (int i = 0; i < F4PT; ++i) {
            float4 v = xr[t + i * TPB];
#pragma unroll
            for (int j = 0; j < 4; ++j) {
                float f = (&v.x)[j];
                unsigned key = keyOf(f);
                if ((key >> s) == p) {
                    unsigned idx = 4u * (unsigned)(t + i * TPB) + (unsigned)j;
                    unsigned pos = atomicAdd(&cnt, 1u);
                    if (pos < CAP1) { candKey[pos] = key; candIdx[pos] = idx; }
                }
            }
        }
        __syncthreads();
        // exact rank (key desc, idx asc == jax top_k tie order); keep r best.
        // Broadcast LDS reads: all lanes read the same q -> conflict-free.
        unsigned m = (E < CAP1) ? E : CAP1;
        for (unsigned q0 = t; q0 < m; q0 += TPB) {
            unsigned k0 = candKey[q0], i0 = candIdx[q0], rank = 0;
            for (unsigned q = 0; q < m; ++q) {
                unsigned kq = candKey[q];
                rank += (kq > k0) || (kq == k0 && candIdx[q] < i0);
            }
            if (rank < r) atomicOr(&bitmap[i0 >> 5], 1u << (i0 & 31));
        }
        __syncthreads();
    }

    // ---------- write (re-read row from L2/L3, nontemporal stores) ----------
#pragma unroll 2
    for (int i = 0; i < F4PT; ++i) {
        float4 v = xr[t + i * TPB];
        f32x4 o;
#pragma unroll
        for (int j = 0; j < 4; ++j) {
            float f = (&v.x)[j];
            unsigned key = keyOf(f);
            unsigned b = key >> s;
            float of = 0.0f;
            if (b > p) {
                of = f;
            } else if (b == p) {
                unsigned idx = 4u * (unsigned)(t + i * TPB) + (unsigned)j;
                if (keepAll || (((bitmap[idx >> 5] >> (idx & 31)) & 1u) != 0u))
                    of = f;
            }
            o[j] = of;
        }
        __builtin_nontemporal_store(o, &orow[t + i * TPB]);
    }
}

extern "C" void kernel_launch(void* const* d_in, const int* in_sizes, int n_in,
                              void* d_out, int out_size, void* d_ws, size_t ws_size,
                              hipStream_t stream) {
    const float* x = (const float*)d_in[0];
    const int* kp = (const int*)d_in[1];
    float* out = (float*)d_out;
    const int rows = in_sizes[0] / NCOLS;   // 4096
    topk_mask_kernel<<<rows, TPB, 0, stream>>>(x, kp, out);
}